// Round 5
// baseline (223.286 us; speedup 1.0000x reference)
//
#include <hip/hip_runtime.h>
#include <cstddef>
#include <cstdint>

#define TPB 256
#define BATCH 65536
#define NREQ 2097152
#define NVEH 1048576
#define NEDGE 4194304
#define CAP 32
#define RANK_NEG ((int)0x80808080)
#define RT 512            // rows per LDS tile
#define SPB 64            // segments per block

__device__ __forceinline__ float fast_tanh(float x) {
    float e = __expf(2.0f * x);
    return 1.0f - 2.0f / (e + 1.0f);
}
__device__ __forceinline__ float4 tanh4(float4 v) {
    return make_float4(fast_tanh(v.x), fast_tanh(v.y), fast_tanh(v.z), fast_tanh(v.w));
}

// ---------------------------------------------------------------------------
// K0: streaming pass: lower-bound tables for both sorted batch arrays,
// vehicle mark bitmask (128 KB -> L1/L2 resident), dense ranks.
// ---------------------------------------------------------------------------
__global__ __launch_bounds__(TPB) void k_bounds(
    const int* __restrict__ req_batch, const int* __restrict__ veh_batch,
    const int* __restrict__ req2veh,
    int* __restrict__ seg_req, int* __restrict__ seg_veh,
    unsigned* __restrict__ markbits, int* __restrict__ rank, int* __restrict__ cnt)
{
    int i = blockIdx.x * TPB + threadIdx.x;
    {
        int cur = req_batch[i];
        int prev = (i == 0) ? -1 : req_batch[i - 1];
        for (int b = prev + 1; b <= cur; ++b) seg_req[b] = i;
        if (i == NREQ - 1)
            for (int b = cur + 1; b <= BATCH; ++b) seg_req[b] = NREQ;
    }
    if (i < NVEH) {
        int cur = veh_batch[i];
        int prev = (i == 0) ? -1 : veh_batch[i - 1];
        for (int b = prev + 1; b <= cur; ++b) seg_veh[b] = i;
        if (i == NVEH - 1)
            for (int b = cur + 1; b <= BATCH; ++b) seg_veh[b] = NVEH;
    }
    if (i < BATCH) {
        int v = req2veh[i];
        atomicOr(&markbits[v >> 5], 1u << (v & 31));
        int old = atomicCAS(&rank[v], RANK_NEG, RANK_NEG + 1);
        if (old == RANK_NEG) rank[v] = atomicAdd(cnt, 1);
    }
}

// ---------------------------------------------------------------------------
// Phase1 worker: block owns SPB consecutive segments; stream the contiguous
// row range through 512-row LDS tiles (coalesced float2 copy), then 4-lane
// teams gather-mean their segment's rows from LDS (broadcast reads,
// stride-5-float2 layout -> 16 teams hit 16 distinct bank pairs).
// ---------------------------------------------------------------------------
template<int F>
__device__ __forceinline__ void phase1_work(
    const float* __restrict__ x, const int* __restrict__ seg,
    const float* __restrict__ W, const float* __restrict__ bias,
    float* __restrict__ mout, int b0, float2* sX, int tid)
{
    constexpr int FP2 = F / 2;              // 5 (req) or 4 (veh)
    int team = tid >> 2, q = tid & 3;
    int b = b0 + team;
    int lo = seg[b], hi = seg[b + 1];
    int lo0 = seg[b0], hi_all = seg[b0 + SPB];

    float4 wq[F];
    #pragma unroll
    for (int i = 0; i < F; ++i)
        wq[i] = *reinterpret_cast<const float4*>(&W[i * 16 + q * 4]);
    float4 bq = reinterpret_cast<const float4*>(bias)[q];

    float4 s = make_float4(0.f, 0.f, 0.f, 0.f);

    for (int rb = lo0; rb < hi_all; rb += RT) {
        int nr = min(RT, hi_all - rb);
        __syncthreads();
        if constexpr (F == 10) {
            const float2* src = reinterpret_cast<const float2*>(x + (size_t)rb * 10);
            for (int i = tid; i < nr * 5; i += TPB) sX[i] = src[i];
        } else {
            const float2* src = reinterpret_cast<const float2*>(x + (size_t)rb * 8);
            for (int idx = tid; idx < nr * 4; idx += TPB) {
                int rr = idx >> 2, i = idx & 3;
                sX[rr * 5 + i] = src[idx];
            }
        }
        __syncthreads();

        int r0 = max(lo, rb), r1 = min(hi, rb + nr);
        for (int r = r0; r < r1; ++r) {
            const float2* row = &sX[(r - rb) * 5];
            float xr[F];
            #pragma unroll
            for (int i = 0; i < FP2; ++i) {
                float2 t = row[i];
                xr[2 * i] = t.x; xr[2 * i + 1] = t.y;
            }
            float4 acc = bq;
            #pragma unroll
            for (int i = 0; i < F; ++i) {
                acc.x = fmaf(xr[i], wq[i].x, acc.x);
                acc.y = fmaf(xr[i], wq[i].y, acc.y);
                acc.z = fmaf(xr[i], wq[i].z, acc.z);
                acc.w = fmaf(xr[i], wq[i].w, acc.w);
            }
            float4 t = tanh4(acc);
            s.x += t.x; s.y += t.y; s.z += t.z; s.w += t.w;
        }
    }
    float inv = 1.0f / fmaxf((float)(hi - lo), 1.0f);
    float4 o = make_float4(s.x * inv, s.y * inv, s.z * inv, s.w * inv);
    reinterpret_cast<float4*>(mout)[(size_t)b * 4 + q] = o;
}

__global__ __launch_bounds__(TPB) void k_phase1(
    const float* __restrict__ requests_x, const int* __restrict__ seg_req,
    const float* __restrict__ vehicles_x, const int* __restrict__ seg_veh,
    const float* __restrict__ W_req, const float* __restrict__ b_req,
    const float* __restrict__ W_veh, const float* __restrict__ b_veh,
    float* __restrict__ req_mean, float* __restrict__ veh_mean)
{
    __shared__ __align__(16) float2 sX[RT * 5];   // 20 KB
    const int NBR = BATCH / SPB;                  // 1024
    int blk = blockIdx.x;
    if (blk < NBR)
        phase1_work<10>(requests_x, seg_req, W_req, b_req, req_mean,
                        blk * SPB, sX, threadIdx.x);
    else
        phase1_work<8>(vehicles_x, seg_veh, W_veh, b_veh, veh_mean,
                       (blk - NBR) * SPB, sX, threadIdx.x);
}

// ---------------------------------------------------------------------------
// K2: scatter marked edges into per-rank buckets. Bitmask gate (128 KB).
// ---------------------------------------------------------------------------
__global__ __launch_bounds__(TPB) void k_edge(
    const int* __restrict__ send, const int* __restrict__ recv,
    const unsigned* __restrict__ markbits, const int* __restrict__ rank,
    int* __restrict__ deg, int* __restrict__ bucket)
{
    int e = blockIdx.x * TPB + threadIdx.x;
    int v = send[e];
    if ((markbits[v >> 5] >> (v & 31)) & 1u) {
        int r = rank[v];
        int slot = atomicAdd(&deg[r], 1);
        if (slot < CAP) bucket[(size_t)r * CAP + slot] = recv[e];
    }
}

// ---------------------------------------------------------------------------
// K3: per-graph head, 4-lane teams.
// ---------------------------------------------------------------------------
__global__ __launch_bounds__(TPB, 3) void k_final(
    const float* __restrict__ req_mean, const float* __restrict__ veh_mean,
    const int* __restrict__ rank, const int* __restrict__ deg,
    const int* __restrict__ bucket, const float* __restrict__ pas_x,
    const float* __restrict__ vehicles_x, const int* __restrict__ req2veh,
    const float* __restrict__ W_veh, const float* __restrict__ b_veh,
    const float* __restrict__ W_pas, const float* __restrict__ b_pas,
    const float* __restrict__ W1, const float* __restrict__ b1,
    const float* __restrict__ W2, const float* __restrict__ b2,
    const float* __restrict__ W3, const float* __restrict__ b3,
    float* __restrict__ out)
{
    __shared__ __align__(16) float sW1[4096];
    __shared__ __align__(16) float sW2[4096];
    __shared__ float sW3[64];
    __shared__ float sb1[64];
    __shared__ float sb2[64];

    int tid = threadIdx.x;
    {
        const float4* s1 = reinterpret_cast<const float4*>(W1);
        const float4* s2 = reinterpret_cast<const float4*>(W2);
        float4* d1 = reinterpret_cast<float4*>(sW1);
        float4* d2 = reinterpret_cast<float4*>(sW2);
        for (int i = tid; i < 1024; i += TPB) { d1[i] = s1[i]; d2[i] = s2[i]; }
        if (tid < 64) { sW3[tid] = W3[tid]; sb1[tid] = b1[tid]; sb2[tid] = b2[tid]; }
    }
    __syncthreads();

    int q = tid & 3;
    int b = blockIdx.x * (TPB / 4) + (tid >> 2);
    int lane = tid & 63;
    int lbase = lane & ~3;

    float a[64];
    {
        const float4* rs = reinterpret_cast<const float4*>(req_mean) + (size_t)b*4;
        const float4* vs = reinterpret_cast<const float4*>(veh_mean) + (size_t)b*4;
        #pragma unroll
        for (int j4 = 0; j4 < 4; ++j4) {
            float4 t = rs[j4];
            a[4*j4+0]=t.x; a[4*j4+1]=t.y; a[4*j4+2]=t.z; a[4*j4+3]=t.w;
            float4 u = vs[j4];
            a[48+4*j4+0]=u.x; a[48+4*j4+1]=u.y; a[48+4*j4+2]=u.z; a[48+4*j4+3]=u.w;
        }
    }
    int v = req2veh[b];

    float4 fv;
    {
        float4 wv[8];
        #pragma unroll
        for (int i = 0; i < 8; ++i)
            wv[i] = *reinterpret_cast<const float4*>(&W_veh[i*16 + q*4]);
        float4 bv = reinterpret_cast<const float4*>(b_veh)[q];
        const float4* vp = reinterpret_cast<const float4*>(vehicles_x + (size_t)v*8);
        float4 t0 = vp[0], t1 = vp[1];
        float vx[8] = {t0.x,t0.y,t0.z,t0.w,t1.x,t1.y,t1.z,t1.w};
        float4 acc = bv;
        #pragma unroll
        for (int i = 0; i < 8; ++i) {
            acc.x = fmaf(vx[i], wv[i].x, acc.x); acc.y = fmaf(vx[i], wv[i].y, acc.y);
            acc.z = fmaf(vx[i], wv[i].z, acc.z); acc.w = fmaf(vx[i], wv[i].w, acc.w);
        }
        fv = tanh4(acc);
    }

    float4 fp;
    {
        float4 wp[10];
        #pragma unroll
        for (int i = 0; i < 10; ++i)
            wp[i] = *reinterpret_cast<const float4*>(&W_pas[i*16 + q*4]);
        float4 bp = reinterpret_cast<const float4*>(b_pas)[q];
        int r = rank[v];
        int d = deg[r];
        int n = min(d, CAP);
        const int* bk = bucket + (size_t)r * CAP;
        float4 ps = make_float4(0.f, 0.f, 0.f, 0.f);
        for (int s = 0; s < n; ++s) {
            int p = bk[s];
            float px[10];
            const float2* pp = reinterpret_cast<const float2*>(pas_x + (size_t)p * 10);
            #pragma unroll
            for (int i = 0; i < 5; ++i) { float2 t = pp[i]; px[2*i] = t.x; px[2*i+1] = t.y; }
            float4 acc = bp;
            #pragma unroll
            for (int i = 0; i < 10; ++i) {
                acc.x = fmaf(px[i], wp[i].x, acc.x); acc.y = fmaf(px[i], wp[i].y, acc.y);
                acc.z = fmaf(px[i], wp[i].z, acc.z); acc.w = fmaf(px[i], wp[i].w, acc.w);
            }
            float4 t = tanh4(acc);
            ps.x += t.x; ps.y += t.y; ps.z += t.z; ps.w += t.w;
        }
        float inv = 1.0f / fmaxf((float)d, 1.0f);
        fp = make_float4(ps.x*inv, ps.y*inv, ps.z*inv, ps.w*inv);
    }

    #pragma unroll
    for (int src = 0; src < 4; ++src) {
        a[16+4*src+0] = __shfl(fv.x, lbase+src);
        a[16+4*src+1] = __shfl(fv.y, lbase+src);
        a[16+4*src+2] = __shfl(fv.z, lbase+src);
        a[16+4*src+3] = __shfl(fv.w, lbase+src);
        a[32+4*src+0] = __shfl(fp.x, lbase+src);
        a[32+4*src+1] = __shfl(fp.y, lbase+src);
        a[32+4*src+2] = __shfl(fp.z, lbase+src);
        a[32+4*src+3] = __shfl(fp.w, lbase+src);
    }

    const float4* W1v = reinterpret_cast<const float4*>(sW1);
    const float4* W2v = reinterpret_cast<const float4*>(sW2);

    float hq[16];
    {
        float4 acc[4];
        #pragma unroll
        for (int jj = 0; jj < 4; ++jj)
            acc[jj] = *reinterpret_cast<const float4*>(&sb1[q*16 + jj*4]);
        #pragma unroll
        for (int k = 0; k < 64; ++k) {
            float ak = a[k];
            #pragma unroll
            for (int jj = 0; jj < 4; ++jj) {
                float4 w = W1v[k*16 + q*4 + jj];
                acc[jj].x = fmaf(ak, w.x, acc[jj].x); acc[jj].y = fmaf(ak, w.y, acc[jj].y);
                acc[jj].z = fmaf(ak, w.z, acc[jj].z); acc[jj].w = fmaf(ak, w.w, acc[jj].w);
            }
        }
        #pragma unroll
        for (int jj = 0; jj < 4; ++jj) {
            float4 t = tanh4(acc[jj]);
            hq[4*jj+0]=t.x; hq[4*jj+1]=t.y; hq[4*jj+2]=t.z; hq[4*jj+3]=t.w;
        }
    }
    #pragma unroll
    for (int src = 0; src < 4; ++src)
        #pragma unroll
        for (int jj = 0; jj < 16; ++jj)
            a[src*16 + jj] = __shfl(hq[jj], lbase + src);

    float o;
    {
        float4 acc[4];
        #pragma unroll
        for (int jj = 0; jj < 4; ++jj)
            acc[jj] = *reinterpret_cast<const float4*>(&sb2[q*16 + jj*4]);
        #pragma unroll
        for (int k = 0; k < 64; ++k) {
            float ak = a[k];
            #pragma unroll
            for (int jj = 0; jj < 4; ++jj) {
                float4 w = W2v[k*16 + q*4 + jj];
                acc[jj].x = fmaf(ak, w.x, acc[jj].x); acc[jj].y = fmaf(ak, w.y, acc[jj].y);
                acc[jj].z = fmaf(ak, w.z, acc[jj].z); acc[jj].w = fmaf(ak, w.w, acc[jj].w);
            }
        }
        o = 0.0f;
        #pragma unroll
        for (int jj = 0; jj < 4; ++jj) {
            float4 t = tanh4(acc[jj]);
            o = fmaf(t.x, sW3[q*16+4*jj+0], o);
            o = fmaf(t.y, sW3[q*16+4*jj+1], o);
            o = fmaf(t.z, sW3[q*16+4*jj+2], o);
            o = fmaf(t.w, sW3[q*16+4*jj+3], o);
        }
    }
    o += __shfl_xor(o, 1);
    o += __shfl_xor(o, 2);
    if (q == 0) out[b] = o + b3[0];
}

// ---------------------------------------------------------------------------
extern "C" void kernel_launch(void* const* d_in, const int* in_sizes, int n_in,
                              void* d_out, int out_size, void* d_ws, size_t ws_size,
                              hipStream_t stream) {
    const float* requests_x = (const float*)d_in[0];
    const int*   req_batch  = (const int*)d_in[1];
    const float* vehicles_x = (const float*)d_in[2];
    const int*   veh_batch  = (const int*)d_in[3];
    const float* pas_x      = (const float*)d_in[4];
    const int*   recv       = (const int*)d_in[5];
    const int*   send       = (const int*)d_in[6];
    const int*   req2veh    = (const int*)d_in[7];
    const float* W_req = (const float*)d_in[8];
    const float* b_req = (const float*)d_in[9];
    const float* W_veh = (const float*)d_in[10];
    const float* b_veh = (const float*)d_in[11];
    const float* W_pas = (const float*)d_in[12];
    const float* b_pas = (const float*)d_in[13];
    const float* W1 = (const float*)d_in[14];
    const float* b1 = (const float*)d_in[15];
    const float* W2 = (const float*)d_in[16];
    const float* b2 = (const float*)d_in[17];
    const float* W3 = (const float*)d_in[18];
    const float* b3 = (const float*)d_in[19];
    float* out = (float*)d_out;

    char* ws = (char*)d_ws;
    float*    req_mean = (float*)   (ws + 0);           //  4 MiB [B,16]
    float*    veh_mean = (float*)   (ws + (4u<<20));    //  4 MiB [B,16]
    int*      seg_req  = (int*)     (ws + (8u<<20));    //  1 MiB [B+1]
    int*      seg_veh  = (int*)     (ws + (9u<<20));    //  1 MiB [B+1]
    unsigned* markbits = (unsigned*)(ws + (10u<<20));   // 128 KiB [NVEH/32]
    int*      rank     = (int*)     (ws + (11u<<20));   //  4 MiB [NVEH]
    int*      deg      = (int*)     (ws + (15u<<20));   // 256 KiB [B]
    int*      cnt      = (int*)     (ws + (15u<<20) + (256u<<10)); // 4 B
    int*      bucket   = (int*)     (ws + (16u<<20));   //  8 MiB [B*CAP]
    // total ws usage: 24 MiB

    hipMemsetAsync(markbits, 0, NVEH / 8, stream);            // bitmask = 0
    hipMemsetAsync(rank, 0x80, NVEH * sizeof(int), stream);   // rank = RANK_NEG
    hipMemsetAsync(deg, 0, (256u<<10) + 64, stream);          // deg = 0, cnt = 0

    k_bounds<<<NREQ/TPB, TPB, 0, stream>>>(
        req_batch, veh_batch, req2veh, seg_req, seg_veh, markbits, rank, cnt);

    k_phase1<<<(BATCH/SPB)*2, TPB, 0, stream>>>(
        requests_x, seg_req, vehicles_x, seg_veh,
        W_req, b_req, W_veh, b_veh, req_mean, veh_mean);

    k_edge<<<NEDGE/TPB, TPB, 0, stream>>>(send, recv, markbits, rank, deg, bucket);

    k_final<<<BATCH*4/TPB, TPB, 0, stream>>>(
        req_mean, veh_mean, rank, deg, bucket, pas_x,
        vehicles_x, req2veh, W_veh, b_veh, W_pas, b_pas,
        W1, b1, W2, b2, W3, b3, out);
}

// Round 6
// 165.799 us; speedup vs baseline: 1.3467x; 1.3467x over previous
//
#include <hip/hip_runtime.h>
#include <cstddef>
#include <cstdint>

#define TPB 256
#define BATCH 65536
#define NREQ 2097152
#define NVEH 1048576
#define NEDGE 4194304
#define CAP 32
#define RANK_NEG ((int)0x80808080)

__device__ __forceinline__ float fast_tanh(float x) {
    float e = __expf(2.0f * x);
    return 1.0f - 2.0f / (e + 1.0f);
}
__device__ __forceinline__ float4 tanh4(float4 v) {
    return make_float4(fast_tanh(v.x), fast_tanh(v.y), fast_tanh(v.z), fast_tanh(v.w));
}

template<int F>
__device__ __forceinline__ void load_row(const float* __restrict__ x, int r, float* xr) {
    if constexpr (F == 10) {
        const float2* p = reinterpret_cast<const float2*>(x + (size_t)r * 10);
        #pragma unroll
        for (int i = 0; i < 5; ++i) { float2 t = p[i]; xr[2*i] = t.x; xr[2*i+1] = t.y; }
    } else {
        const float4* p = reinterpret_cast<const float4*>(x + (size_t)r * 8);
        float4 a = p[0], b = p[1];
        xr[0]=a.x; xr[1]=a.y; xr[2]=a.z; xr[3]=a.w;
        xr[4]=b.x; xr[5]=b.y; xr[6]=b.z; xr[7]=b.w;
    }
}

// ---------------------------------------------------------------------------
// K0: streaming pass (4 rows/thread, int4 loads): lower-bound tables for both
// sorted batch arrays, vehicle mark bitmask, dense rank claims.
// ---------------------------------------------------------------------------
__global__ __launch_bounds__(TPB) void k_bounds(
    const int* __restrict__ req_batch, const int* __restrict__ veh_batch,
    const int* __restrict__ req2veh,
    int* __restrict__ seg_req, int* __restrict__ seg_veh,
    unsigned* __restrict__ markbits, int* __restrict__ rank, int* __restrict__ cnt)
{
    int t = blockIdx.x * TPB + threadIdx.x;
    int i0 = t * 4;
    {
        int4 c = *reinterpret_cast<const int4*>(req_batch + i0);
        int prev = (i0 == 0) ? -1 : req_batch[i0 - 1];
        int vals[4] = {c.x, c.y, c.z, c.w};
        #pragma unroll
        for (int u = 0; u < 4; ++u) {
            for (int b = prev + 1; b <= vals[u]; ++b) seg_req[b] = i0 + u;
            prev = vals[u];
        }
        if (i0 + 4 == NREQ)
            for (int b = prev + 1; b <= BATCH; ++b) seg_req[b] = NREQ;
    }
    if (i0 < NVEH) {
        int4 c = *reinterpret_cast<const int4*>(veh_batch + i0);
        int prev = (i0 == 0) ? -1 : veh_batch[i0 - 1];
        int vals[4] = {c.x, c.y, c.z, c.w};
        #pragma unroll
        for (int u = 0; u < 4; ++u) {
            for (int b = prev + 1; b <= vals[u]; ++b) seg_veh[b] = i0 + u;
            prev = vals[u];
        }
        if (i0 + 4 == NVEH)
            for (int b = prev + 1; b <= BATCH; ++b) seg_veh[b] = NVEH;
    }
    if (i0 < BATCH) {
        int4 vv = *reinterpret_cast<const int4*>(req2veh + i0);
        int vs[4] = {vv.x, vv.y, vv.z, vv.w};
        #pragma unroll
        for (int u = 0; u < 4; ++u) {
            int v = vs[u];
            atomicOr(&markbits[v >> 5], 1u << (v & 31));
            int old = atomicCAS(&rank[v], RANK_NEG, RANK_NEG + 1);
            if (old == RANK_NEG) rank[v] = atomicAdd(cnt, 1);
        }
    }
}

// ---------------------------------------------------------------------------
// Segment-mean, register weights, 4-row unrolled (loads batched for ILP).
// 4 lanes per segment, lane q owns output columns [4q,4q+4).
// ---------------------------------------------------------------------------
template<int F>
__device__ __forceinline__ void seg_mean_reg(
    const float* __restrict__ x, const int* __restrict__ seg,
    const float* __restrict__ W, const float* __restrict__ bias,
    float* __restrict__ mean_out, int b, int q)
{
    float4 wq[F];
    #pragma unroll
    for (int i = 0; i < F; ++i)
        wq[i] = *reinterpret_cast<const float4*>(&W[i*16 + q*4]);
    float4 bq = reinterpret_cast<const float4*>(bias)[q];

    int lo = seg[b];
    int hi = seg[b + 1];
    float4 s = make_float4(0.f, 0.f, 0.f, 0.f);

    int r = lo;
    for (; r + 4 <= hi; r += 4) {
        float xr[4][F];
        #pragma unroll
        for (int u = 0; u < 4; ++u) load_row<F>(x, r + u, xr[u]);
        #pragma unroll
        for (int u = 0; u < 4; ++u) {
            float4 acc = bq;
            #pragma unroll
            for (int i = 0; i < F; ++i) {
                acc.x = fmaf(xr[u][i], wq[i].x, acc.x);
                acc.y = fmaf(xr[u][i], wq[i].y, acc.y);
                acc.z = fmaf(xr[u][i], wq[i].z, acc.z);
                acc.w = fmaf(xr[u][i], wq[i].w, acc.w);
            }
            float4 tv = tanh4(acc);
            s.x += tv.x; s.y += tv.y; s.z += tv.z; s.w += tv.w;
        }
    }
    for (; r < hi; ++r) {
        float xr[F];
        load_row<F>(x, r, xr);
        float4 acc = bq;
        #pragma unroll
        for (int i = 0; i < F; ++i) {
            acc.x = fmaf(xr[i], wq[i].x, acc.x);
            acc.y = fmaf(xr[i], wq[i].y, acc.y);
            acc.z = fmaf(xr[i], wq[i].z, acc.z);
            acc.w = fmaf(xr[i], wq[i].w, acc.w);
        }
        float4 tv = tanh4(acc);
        s.x += tv.x; s.y += tv.y; s.z += tv.z; s.w += tv.w;
    }
    float inv = 1.0f / fmaxf((float)(hi - lo), 1.0f);
    float4 o = make_float4(s.x*inv, s.y*inv, s.z*inv, s.w*inv);
    reinterpret_cast<float4*>(mean_out)[(size_t)b*4 + q] = o;
}

// ---------------------------------------------------------------------------
// K_MID: fused phase1 (req mean | veh mean) + edge scatter.
// phase1 blocks first (long-running), edge blocks fill in behind them so the
// random-gather memory time hides under phase1's compute.
// ---------------------------------------------------------------------------
#define NB_REQ (BATCH/64)                       // 1024
#define NB_VEH (BATCH/64)                       // 1024
#define NB_P1  (NB_REQ + NB_VEH)                // 2048
#define NB_EDGE (NEDGE/(TPB*4))                 // 4096

__global__ __launch_bounds__(TPB, 4) void k_mid(
    const float* __restrict__ requests_x, const int* __restrict__ seg_req,
    const float* __restrict__ vehicles_x, const int* __restrict__ seg_veh,
    const float* __restrict__ W_req, const float* __restrict__ b_req,
    const float* __restrict__ W_veh, const float* __restrict__ b_veh,
    float* __restrict__ req_mean, float* __restrict__ veh_mean,
    const int* __restrict__ send, const int* __restrict__ recv,
    const unsigned* __restrict__ markbits, const int* __restrict__ rank,
    int* __restrict__ deg, int* __restrict__ bucket)
{
    int blk = blockIdx.x;
    int tid = threadIdx.x;
    if (blk < NB_REQ) {
        int t = blk * TPB + tid;
        seg_mean_reg<10>(requests_x, seg_req, W_req, b_req, req_mean, t >> 2, t & 3);
    } else if (blk < NB_P1) {
        int t = (blk - NB_REQ) * TPB + tid;
        seg_mean_reg<8>(vehicles_x, seg_veh, W_veh, b_veh, veh_mean, t >> 2, t & 3);
    } else {
        int e4 = (blk - NB_P1) * TPB + tid;
        int4 sv = reinterpret_cast<const int4*>(send)[e4];
        int vv[4] = {sv.x, sv.y, sv.z, sv.w};
        #pragma unroll
        for (int u = 0; u < 4; ++u) {
            int v = vv[u];
            if ((markbits[v >> 5] >> (v & 31)) & 1u) {
                int rk = rank[v];
                int slot = atomicAdd(&deg[rk], 1);
                if (slot < CAP) bucket[(size_t)rk * CAP + slot] = recv[e4 * 4 + u];
            }
        }
    }
}

// ---------------------------------------------------------------------------
// K3: per-graph head, 4-lane teams; bucket walk chunked via int4 (4 rows ILP).
// ---------------------------------------------------------------------------
__global__ __launch_bounds__(TPB, 3) void k_final(
    const float* __restrict__ req_mean, const float* __restrict__ veh_mean,
    const int* __restrict__ rank, const int* __restrict__ deg,
    const int* __restrict__ bucket, const float* __restrict__ pas_x,
    const float* __restrict__ vehicles_x, const int* __restrict__ req2veh,
    const float* __restrict__ W_veh, const float* __restrict__ b_veh,
    const float* __restrict__ W_pas, const float* __restrict__ b_pas,
    const float* __restrict__ W1, const float* __restrict__ b1,
    const float* __restrict__ W2, const float* __restrict__ b2,
    const float* __restrict__ W3, const float* __restrict__ b3,
    float* __restrict__ out)
{
    __shared__ __align__(16) float sW1[4096];
    __shared__ __align__(16) float sW2[4096];
    __shared__ float sW3[64];
    __shared__ float sb1[64];
    __shared__ float sb2[64];

    int tid = threadIdx.x;
    {
        const float4* s1 = reinterpret_cast<const float4*>(W1);
        const float4* s2 = reinterpret_cast<const float4*>(W2);
        float4* d1 = reinterpret_cast<float4*>(sW1);
        float4* d2 = reinterpret_cast<float4*>(sW2);
        for (int i = tid; i < 1024; i += TPB) { d1[i] = s1[i]; d2[i] = s2[i]; }
        if (tid < 64) { sW3[tid] = W3[tid]; sb1[tid] = b1[tid]; sb2[tid] = b2[tid]; }
    }
    __syncthreads();

    int q = tid & 3;
    int b = blockIdx.x * (TPB / 4) + (tid >> 2);
    int lane = tid & 63;
    int lbase = lane & ~3;

    float a[64];
    {
        const float4* rs = reinterpret_cast<const float4*>(req_mean) + (size_t)b*4;
        const float4* vs = reinterpret_cast<const float4*>(veh_mean) + (size_t)b*4;
        #pragma unroll
        for (int j4 = 0; j4 < 4; ++j4) {
            float4 t = rs[j4];
            a[4*j4+0]=t.x; a[4*j4+1]=t.y; a[4*j4+2]=t.z; a[4*j4+3]=t.w;
            float4 u = vs[j4];
            a[48+4*j4+0]=u.x; a[48+4*j4+1]=u.y; a[48+4*j4+2]=u.z; a[48+4*j4+3]=u.w;
        }
    }
    int v = req2veh[b];

    float4 fv;
    {
        float4 wv[8];
        #pragma unroll
        for (int i = 0; i < 8; ++i)
            wv[i] = *reinterpret_cast<const float4*>(&W_veh[i*16 + q*4]);
        float4 bv = reinterpret_cast<const float4*>(b_veh)[q];
        float vx[8];
        load_row<8>(vehicles_x, v, vx);
        float4 acc = bv;
        #pragma unroll
        for (int i = 0; i < 8; ++i) {
            acc.x = fmaf(vx[i], wv[i].x, acc.x); acc.y = fmaf(vx[i], wv[i].y, acc.y);
            acc.z = fmaf(vx[i], wv[i].z, acc.z); acc.w = fmaf(vx[i], wv[i].w, acc.w);
        }
        fv = tanh4(acc);
    }

    float4 fp;
    {
        float4 wp[10];
        #pragma unroll
        for (int i = 0; i < 10; ++i)
            wp[i] = *reinterpret_cast<const float4*>(&W_pas[i*16 + q*4]);
        float4 bp = reinterpret_cast<const float4*>(b_pas)[q];
        int r = rank[v];
        int d = deg[r];
        int n = min(d, CAP);
        const int4* bk4 = reinterpret_cast<const int4*>(bucket + (size_t)r * CAP);
        float4 ps = make_float4(0.f, 0.f, 0.f, 0.f);
        for (int c = 0; c * 4 < n; ++c) {
            int4 idx = bk4[c];
            int pv[4] = {idx.x, idx.y, idx.z, idx.w};
            int m = n - c * 4;
            float px[4][10];
            #pragma unroll
            for (int u = 0; u < 4; ++u)
                if (u < m) load_row<10>(pas_x, pv[u], px[u]);
            #pragma unroll
            for (int u = 0; u < 4; ++u) {
                if (u < m) {
                    float4 acc = bp;
                    #pragma unroll
                    for (int i = 0; i < 10; ++i) {
                        acc.x = fmaf(px[u][i], wp[i].x, acc.x);
                        acc.y = fmaf(px[u][i], wp[i].y, acc.y);
                        acc.z = fmaf(px[u][i], wp[i].z, acc.z);
                        acc.w = fmaf(px[u][i], wp[i].w, acc.w);
                    }
                    float4 t = tanh4(acc);
                    ps.x += t.x; ps.y += t.y; ps.z += t.z; ps.w += t.w;
                }
            }
        }
        float inv = 1.0f / fmaxf((float)d, 1.0f);
        fp = make_float4(ps.x*inv, ps.y*inv, ps.z*inv, ps.w*inv);
    }

    #pragma unroll
    for (int src = 0; src < 4; ++src) {
        a[16+4*src+0] = __shfl(fv.x, lbase+src);
        a[16+4*src+1] = __shfl(fv.y, lbase+src);
        a[16+4*src+2] = __shfl(fv.z, lbase+src);
        a[16+4*src+3] = __shfl(fv.w, lbase+src);
        a[32+4*src+0] = __shfl(fp.x, lbase+src);
        a[32+4*src+1] = __shfl(fp.y, lbase+src);
        a[32+4*src+2] = __shfl(fp.z, lbase+src);
        a[32+4*src+3] = __shfl(fp.w, lbase+src);
    }

    const float4* W1v = reinterpret_cast<const float4*>(sW1);
    const float4* W2v = reinterpret_cast<const float4*>(sW2);

    float hq[16];
    {
        float4 acc[4];
        #pragma unroll
        for (int jj = 0; jj < 4; ++jj)
            acc[jj] = *reinterpret_cast<const float4*>(&sb1[q*16 + jj*4]);
        #pragma unroll
        for (int k = 0; k < 64; ++k) {
            float ak = a[k];
            #pragma unroll
            for (int jj = 0; jj < 4; ++jj) {
                float4 w = W1v[k*16 + q*4 + jj];
                acc[jj].x = fmaf(ak, w.x, acc[jj].x); acc[jj].y = fmaf(ak, w.y, acc[jj].y);
                acc[jj].z = fmaf(ak, w.z, acc[jj].z); acc[jj].w = fmaf(ak, w.w, acc[jj].w);
            }
        }
        #pragma unroll
        for (int jj = 0; jj < 4; ++jj) {
            float4 t = tanh4(acc[jj]);
            hq[4*jj+0]=t.x; hq[4*jj+1]=t.y; hq[4*jj+2]=t.z; hq[4*jj+3]=t.w;
        }
    }
    #pragma unroll
    for (int src = 0; src < 4; ++src)
        #pragma unroll
        for (int jj = 0; jj < 16; ++jj)
            a[src*16 + jj] = __shfl(hq[jj], lbase + src);

    float o;
    {
        float4 acc[4];
        #pragma unroll
        for (int jj = 0; jj < 4; ++jj)
            acc[jj] = *reinterpret_cast<const float4*>(&sb2[q*16 + jj*4]);
        #pragma unroll
        for (int k = 0; k < 64; ++k) {
            float ak = a[k];
            #pragma unroll
            for (int jj = 0; jj < 4; ++jj) {
                float4 w = W2v[k*16 + q*4 + jj];
                acc[jj].x = fmaf(ak, w.x, acc[jj].x); acc[jj].y = fmaf(ak, w.y, acc[jj].y);
                acc[jj].z = fmaf(ak, w.z, acc[jj].z); acc[jj].w = fmaf(ak, w.w, acc[jj].w);
            }
        }
        o = 0.0f;
        #pragma unroll
        for (int jj = 0; jj < 4; ++jj) {
            float4 t = tanh4(acc[jj]);
            o = fmaf(t.x, sW3[q*16+4*jj+0], o);
            o = fmaf(t.y, sW3[q*16+4*jj+1], o);
            o = fmaf(t.z, sW3[q*16+4*jj+2], o);
            o = fmaf(t.w, sW3[q*16+4*jj+3], o);
        }
    }
    o += __shfl_xor(o, 1);
    o += __shfl_xor(o, 2);
    if (q == 0) out[b] = o + b3[0];
}

// ---------------------------------------------------------------------------
extern "C" void kernel_launch(void* const* d_in, const int* in_sizes, int n_in,
                              void* d_out, int out_size, void* d_ws, size_t ws_size,
                              hipStream_t stream) {
    const float* requests_x = (const float*)d_in[0];
    const int*   req_batch  = (const int*)d_in[1];
    const float* vehicles_x = (const float*)d_in[2];
    const int*   veh_batch  = (const int*)d_in[3];
    const float* pas_x      = (const float*)d_in[4];
    const int*   recv       = (const int*)d_in[5];
    const int*   send       = (const int*)d_in[6];
    const int*   req2veh    = (const int*)d_in[7];
    const float* W_req = (const float*)d_in[8];
    const float* b_req = (const float*)d_in[9];
    const float* W_veh = (const float*)d_in[10];
    const float* b_veh = (const float*)d_in[11];
    const float* W_pas = (const float*)d_in[12];
    const float* b_pas = (const float*)d_in[13];
    const float* W1 = (const float*)d_in[14];
    const float* b1 = (const float*)d_in[15];
    const float* W2 = (const float*)d_in[16];
    const float* b2 = (const float*)d_in[17];
    const float* W3 = (const float*)d_in[18];
    const float* b3 = (const float*)d_in[19];
    float* out = (float*)d_out;

    char* ws = (char*)d_ws;
    float*    req_mean = (float*)   (ws + 0);                        //  4 MiB
    float*    veh_mean = (float*)   (ws + (4u<<20));                 //  4 MiB
    int*      seg_req  = (int*)     (ws + (8u<<20));                 //  1 MiB
    int*      seg_veh  = (int*)     (ws + (9u<<20));                 //  1 MiB
    unsigned* markbits = (unsigned*)(ws + (10u<<20));                // 128 KiB
    int*      deg      = (int*)     (ws + (10u<<20) + (128u<<10));   // 256 KiB
    int*      cnt      = (int*)     (ws + (10u<<20) + (384u<<10));   // 64 B
    int*      rank     = (int*)     (ws + (11u<<20));                //  4 MiB
    int*      bucket   = (int*)     (ws + (15u<<20));                //  8 MiB
    // total ws usage: 23 MiB

    // one contiguous zero region: markbits + deg + cnt
    hipMemsetAsync(markbits, 0, (384u<<10) + 64, stream);
    hipMemsetAsync(rank, 0x80, NVEH * sizeof(int), stream);          // RANK_NEG

    k_bounds<<<NREQ/4/TPB, TPB, 0, stream>>>(
        req_batch, veh_batch, req2veh, seg_req, seg_veh, markbits, rank, cnt);

    k_mid<<<NB_P1 + NB_EDGE, TPB, 0, stream>>>(
        requests_x, seg_req, vehicles_x, seg_veh,
        W_req, b_req, W_veh, b_veh, req_mean, veh_mean,
        send, recv, markbits, rank, deg, bucket);

    k_final<<<BATCH*4/TPB, TPB, 0, stream>>>(
        req_mean, veh_mean, rank, deg, bucket, pas_x,
        vehicles_x, req2veh, W_veh, b_veh, W_pas, b_pas,
        W1, b1, W2, b2, W3, b3, out);
}